// Round 2
// baseline (1335.140 us; speedup 1.0000x reference)
//
#include <hip/hip_runtime.h>

typedef __bf16 bf16;
typedef bf16 bf16x8 __attribute__((ext_vector_type(8)));
typedef bf16 bf16x4 __attribute__((ext_vector_type(4)));
typedef float floatx4 __attribute__((ext_vector_type(4)));

#define D_MODEL 1024
#define SEQ     2048
#define NB      4
#define NH      16
#define DKH     64
// log2(10000)/32
#define ROPE_L2 0.4152410118609203f

__device__ __forceinline__ floatx4 mfma16(bf16x8 a, bf16x8 b, floatx4 c) {
  return __builtin_amdgcn_mfma_f32_16x16x32_bf16(a, b, c, 0, 0, 0);
}

// Async global->LDS, 16B per lane. lds base must be wave-uniform; HW adds lane*16.
__device__ __forceinline__ void gload_lds16(void* lds_uniform, const void* gsrc) {
  __builtin_amdgcn_global_load_lds(
      (__attribute__((address_space(1))) unsigned int*)(void*)(gsrc),
      (__attribute__((address_space(3))) unsigned int*)lds_uniform,
      16, 0, 0);
}

// ---------------- fp32 -> bf16 conversion ----------------
__global__ __launch_bounds__(256) void cvt_f32_bf16(const float4* __restrict__ src,
                                                    bf16x4* __restrict__ dst, int n4) {
  int i = blockIdx.x * 256 + threadIdx.x;
  if (i >= n4) return;
  float4 v = src[i];
  bf16x4 o;
  o[0] = (bf16)v.x; o[1] = (bf16)v.y; o[2] = (bf16)v.z; o[3] = (bf16)v.w;
  dst[i] = o;
}

// ---------------- GEMM mainloop as a MACRO ----------------
// C(128x128) = A[M,K] @ W[N,K]^T, K=1024, BK=32. As/Bs row-major [128][32] bf16.
// 4 waves, each computes 64x64 (4x4 frags of 16x16x32).
// MUST be textually inlined: passing acc[][] through a function param made the
// alloca address-taken -> never SROA'd -> accumulator lived in scratch
// (observed: VGPR_Count=32, WRITE_SIZE=3.3GB, 48 TF).
#define GEMM_MAINLOOP(Aptr, Bptr)                                              \
  for (int kt = 0; kt < 32; ++kt) {                                            \
    const int k0 = kt * 32;                                                    \
    __syncthreads();                                                           \
    _Pragma("unroll")                                                          \
    for (int j = 0; j < 2; ++j) {                                              \
      const int c = w * 64 + lane + 256 * j;                                   \
      const int row = c >> 2, seg = c & 3;                                     \
      gload_lds16((char*)As + (w * 64 + 256 * j) * 16,                         \
                  (Aptr) + (size_t)(bm + row) * D_MODEL + k0 + seg * 8);       \
      gload_lds16((char*)Bs + (w * 64 + 256 * j) * 16,                         \
                  (Bptr) + (size_t)(bn + row) * D_MODEL + k0 + seg * 8);       \
    }                                                                          \
    __syncthreads();                                                           \
    bf16x8 af[4], bff[4];                                                      \
    _Pragma("unroll")                                                          \
    for (int m = 0; m < 4; ++m)                                                \
      af[m] = *(const bf16x8*)&As[(wr * 64 + m * 16 + r) * 32 + g * 8];        \
    _Pragma("unroll")                                                          \
    for (int n = 0; n < 4; ++n)                                                \
      bff[n] = *(const bf16x8*)&Bs[(wc * 64 + n * 16 + r) * 32 + g * 8];       \
    _Pragma("unroll")                                                          \
    for (int m = 0; m < 4; ++m)                                                \
      _Pragma("unroll")                                                        \
      for (int n = 0; n < 4; ++n)                                              \
        acc[m][n] = mfma16(af[m], bff[n], acc[m][n]);                          \
  }

// ---------------- QKV projection, RoPE fused, layout transform ----------------
// z=0: Q -> Qd [B,H,S,dk] (RoPE). z=1: K -> Kd (RoPE). z=2: V -> Vd [B,H,dk,S] (transposed).
__global__ __launch_bounds__(256) void gemm_qkv(
    const bf16* __restrict__ A,
    const bf16* __restrict__ W0, const bf16* __restrict__ W1, const bf16* __restrict__ W2,
    bf16* __restrict__ Qd, bf16* __restrict__ Kd, bf16* __restrict__ Vd,
    const int* __restrict__ tokpos) {
  __shared__ bf16 As[128 * 32];
  __shared__ bf16 Bs[128 * 32];
  const int z = blockIdx.z;
  const bf16* Bw = (z == 0) ? W0 : (z == 1) ? W1 : W2;
  const int tid = threadIdx.x, lane = tid & 63, w = tid >> 6;
  const int wr = w >> 1, wc = w & 1;
  const int bm = blockIdx.y * 128, bn = blockIdx.x * 128;
  const int r = lane & 15, g = lane >> 4;
  floatx4 acc[4][4] = {};
  GEMM_MAINLOOP(A, Bw)

#pragma unroll
  for (int m = 0; m < 4; ++m) {
#pragma unroll
    for (int n = 0; n < 4; ++n) {
#pragma unroll
      for (int reg = 0; reg < 4; ++reg) {
        const int grow = bm + wr * 64 + m * 16 + g * 4 + reg;  // b*S + s
        const int gcol = bn + wc * 64 + n * 16 + r;            // h*64 + d
        const int b = grow >> 11, s = grow & (SEQ - 1);
        const int h = gcol >> 6, d = gcol & 63;
        float v = acc[m][n][reg];
        if (z < 2) {
          // interleaved-pair RoPE: partner column is lane^1 (same frag/reg)
          float p = __shfl_xor(v, 1);
          const int i2 = d >> 1;
          float ang = (float)tokpos[s] * exp2f(-(float)i2 * ROPE_L2);
          float sn, cs;
          sincosf(ang, &sn, &cs);
          float res = ((d & 1) == 0) ? (cs * v - sn * p) : (sn * p + cs * v);
          bf16* dst = (z == 0) ? Qd : Kd;
          dst[(((size_t)(b * NH + h)) * SEQ + s) * DKH + d] = (bf16)res;
        } else {
          Vd[(((size_t)(b * NH + h)) * DKH + d) * SEQ + s] = (bf16)v;
        }
      }
    }
  }
}

// ---------------- output projection: d_out = AO @ Wo^T (fp32 row-major) ----------------
__global__ __launch_bounds__(256) void gemm_out(const bf16* __restrict__ A,
                                                const bf16* __restrict__ Bw,
                                                float* __restrict__ C) {
  __shared__ bf16 As[128 * 32];
  __shared__ bf16 Bs[128 * 32];
  const int tid = threadIdx.x, lane = tid & 63, w = tid >> 6;
  const int wr = w >> 1, wc = w & 1;
  const int bm = blockIdx.y * 128, bn = blockIdx.x * 128;
  const int r = lane & 15, g = lane >> 4;
  floatx4 acc[4][4] = {};
  GEMM_MAINLOOP(A, Bw)
#pragma unroll
  for (int m = 0; m < 4; ++m)
#pragma unroll
    for (int n = 0; n < 4; ++n)
#pragma unroll
      for (int reg = 0; reg < 4; ++reg) {
        const int grow = bm + wr * 64 + m * 16 + g * 4 + reg;
        const int gcol = bn + wc * 64 + n * 16 + r;
        C[(size_t)grow * D_MODEL + gcol] = acc[m][n][reg];
      }
}

// ---------------- causal flash attention ----------------
// grid (32, 64): x = q-tile of 64 rows, y = b*16+h. 4 waves x 16 q-rows.
// Q [B,H,S,64] bf16; K [B,H,S,64] bf16; Vt [B,H,64,S] bf16. AO [B,S,1024] bf16.
__global__ __launch_bounds__(256) void attn64(const bf16* __restrict__ Q,
                                              const bf16* __restrict__ Kk,
                                              const bf16* __restrict__ Vt,
                                              bf16* __restrict__ AO) {
  const int bh = blockIdx.y;
  const int b = bh >> 4, h = bh & 15;
  const int qt = blockIdx.x;
  const int tid = threadIdx.x, lane = tid & 63, w = tid >> 6;
  const int r = lane & 15, g = lane >> 4;
  const int q0 = qt * 64 + w * 16;

  const bf16* Qb = Q + ((size_t)bh * SEQ) * DKH;
  const bf16* Kb = Kk + ((size_t)bh * SEQ) * DKH;
  const bf16* Vb = Vt + ((size_t)bh * DKH) * SEQ;

  __shared__ bf16 Ks[64 * 64];     // [token][d], XOR-swizzled
  __shared__ bf16 Vs[64 * 64];     // [d][token], XOR-swizzled
  __shared__ bf16 Ps[4][16 * 64];  // per-wave P, XOR-swizzled

  bf16x8 qf[2];
#pragma unroll
  for (int ks = 0; ks < 2; ++ks)
    qf[ks] = *(const bf16x8*)(Qb + (size_t)(q0 + r) * DKH + ks * 32 + g * 8);

  floatx4 o[4] = {};
  float m_[4], l_[4];
#pragma unroll
  for (int i = 0; i < 4; ++i) { m_[i] = -1e30f; l_[i] = 0.f; }

  const int nt = qt + 1;
  for (int t = 0; t < nt; ++t) {
    const int t0 = t * 64;
    __syncthreads();
    // stage K (8KB contiguous) and V^T (64 rows x 128B, row stride 4KB), source pre-swizzled
#pragma unroll
    for (int j = 0; j < 2; ++j) {
      const int L = (w * 64 + lane + 256 * j) * 16;
      const int S = L ^ (((L >> 7) & 7) << 4);
      gload_lds16((char*)Ks + (w * 64 + 256 * j) * 16,
                  (const char*)(Kb + (size_t)t0 * DKH) + S);
      const int row = S >> 7, seg = S & 127;
      gload_lds16((char*)Vs + (w * 64 + 256 * j) * 16,
                  (const char*)Vb + (size_t)row * (SEQ * 2) + t0 * 2 + seg);
    }
    __syncthreads();

    // scores = Q @ K^T  (16 q-rows x 64 tokens)
    floatx4 sc[4];
#pragma unroll
    for (int nf = 0; nf < 4; ++nf) {
      sc[nf] = floatx4{0.f, 0.f, 0.f, 0.f};
#pragma unroll
      for (int ks = 0; ks < 2; ++ks) {
        const int row = nf * 16 + r;
        int byteoff = row * 128 + ks * 64 + g * 16;
        byteoff ^= ((row & 7) << 4);
        bf16x8 kf = *(const bf16x8*)((const char*)Ks + byteoff);
        sc[nf] = mfma16(qf[ks], kf, sc[nf]);
      }
    }

    const bool edge = (t0 + 63 > q0);
#pragma unroll
    for (int reg = 0; reg < 4; ++reg) {
      const int qrow = q0 + g * 4 + reg;
      float mx = -1e30f;
#pragma unroll
      for (int nf = 0; nf < 4; ++nf) {
        float s = sc[nf][reg] * 0.125f;  // 1/sqrt(64)
        if (edge && (t0 + nf * 16 + r > qrow)) s = -1e30f;
        sc[nf][reg] = s;
        mx = fmaxf(mx, s);
      }
#pragma unroll
      for (int off = 1; off < 16; off <<= 1) mx = fmaxf(mx, __shfl_xor(mx, off));
      const float mnew = fmaxf(m_[reg], mx);
      const float corr = __expf(m_[reg] - mnew);
      float rs = 0.f;
      const int prow = g * 4 + reg;
#pragma unroll
      for (int nf = 0; nf < 4; ++nf) {
        float p = __expf(sc[nf][reg] - mnew);
        rs += p;
        int pb = prow * 128 + (nf * 16 + r) * 2;
        pb ^= ((prow & 7) << 4);
        *(bf16*)((char*)Ps[w] + pb) = (bf16)p;
      }
#pragma unroll
      for (int off = 1; off < 16; off <<= 1) rs += __shfl_xor(rs, off);
      l_[reg] = l_[reg] * corr + rs;
      m_[reg] = mnew;
#pragma unroll
      for (int nf = 0; nf < 4; ++nf) o[nf][reg] *= corr;
    }
    // make P writes visible across lanes of this wave before ds_read
    asm volatile("s_waitcnt lgkmcnt(0)" ::: "memory");

    // O += P @ V
#pragma unroll
    for (int nf = 0; nf < 4; ++nf) {
#pragma unroll
      for (int ks = 0; ks < 2; ++ks) {
        int ab = r * 128 + ks * 64 + g * 16;
        ab ^= ((r & 7) << 4);
        bf16x8 pf = *(const bf16x8*)((const char*)Ps[w] + ab);
        const int vrow = nf * 16 + r;
        int vb = vrow * 128 + ks * 64 + g * 16;
        vb ^= ((vrow & 7) << 4);
        bf16x8 vf = *(const bf16x8*)((const char*)Vs + vb);
        o[nf] = mfma16(pf, vf, o[nf]);
      }
    }
  }

  // finalize and write AO[b, s, h*64+d]
#pragma unroll
  for (int nf = 0; nf < 4; ++nf)
#pragma unroll
    for (int reg = 0; reg < 4; ++reg) {
      const int s = q0 + g * 4 + reg;
      const int d = nf * 16 + r;
      const float val = o[nf][reg] / l_[reg];
      AO[((size_t)(b * SEQ + s)) * D_MODEL + h * DKH + d] = (bf16)val;
    }
}

// ---------------- launcher ----------------
extern "C" void kernel_launch(void* const* d_in, const int* in_sizes, int n_in,
                              void* d_out, int out_size, void* d_ws, size_t ws_size,
                              hipStream_t stream) {
  const float* x = (const float*)d_in[0];
  const int* tokpos = (const int*)d_in[1];
  const float* Wq = (const float*)d_in[2];
  const float* Wk = (const float*)d_in[3];
  const float* Wv = (const float*)d_in[4];
  const float* Wo = (const float*)d_in[5];
  float* out = (float*)d_out;

  char* ws = (char*)d_ws;
  if (ws_size < (72ull << 20)) return;  // need 72 MiB scratch

  bf16* xb  = (bf16*)(ws);                     // 16 MiB [8192,1024]
  bf16* wb0 = (bf16*)(ws + (16ull << 20));     // 2 MiB each
  bf16* wb1 = (bf16*)(ws + (18ull << 20));
  bf16* wb2 = (bf16*)(ws + (20ull << 20));
  bf16* wb3 = (bf16*)(ws + (22ull << 20));
  bf16* Qb  = (bf16*)(ws + (24ull << 20));     // 16 MiB [B,H,S,64]
  bf16* Kb  = (bf16*)(ws + (40ull << 20));     // 16 MiB
  bf16* Vt  = (bf16*)(ws + (56ull << 20));     // 16 MiB [B,H,64,S]
  bf16* AO  = (bf16*)(ws);                     // reuse xb region (dead after QKV)

  cvt_f32_bf16<<<8192, 256, 0, stream>>>((const float4*)x, (bf16x4*)xb, 2097152);
  cvt_f32_bf16<<<1024, 256, 0, stream>>>((const float4*)Wq, (bf16x4*)wb0, 262144);
  cvt_f32_bf16<<<1024, 256, 0, stream>>>((const float4*)Wk, (bf16x4*)wb1, 262144);
  cvt_f32_bf16<<<1024, 256, 0, stream>>>((const float4*)Wv, (bf16x4*)wb2, 262144);
  cvt_f32_bf16<<<1024, 256, 0, stream>>>((const float4*)Wo, (bf16x4*)wb3, 262144);

  gemm_qkv<<<dim3(8, 64, 3), 256, 0, stream>>>(xb, wb0, wb1, wb2, Qb, Kb, Vt, tokpos);
  attn64<<<dim3(32, 64), 256, 0, stream>>>(Qb, Kb, Vt, AO);
  gemm_out<<<dim3(8, 64), 256, 0, stream>>>(AO, wb3, out);
}

// Round 3
// 357.236 us; speedup vs baseline: 3.7374x; 3.7374x over previous
//
#include <hip/hip_runtime.h>

typedef __bf16 bf16;
typedef bf16 bf16x8 __attribute__((ext_vector_type(8)));
typedef bf16 bf16x4 __attribute__((ext_vector_type(4)));
typedef float floatx4 __attribute__((ext_vector_type(4)));

#define D_MODEL 1024
#define SEQ     2048
#define NB      4
#define NH      16
#define DKH     64
// log2(10000)/32
#define ROPE_L2 0.4152410118609203f

__device__ __forceinline__ floatx4 mfma16(bf16x8 a, bf16x8 b, floatx4 c) {
  return __builtin_amdgcn_mfma_f32_16x16x32_bf16(a, b, c, 0, 0, 0);
}

// Async global->LDS, 16B per lane. lds base must be wave-uniform; HW adds lane*16.
__device__ __forceinline__ void gload_lds16(void* lds_uniform, const void* gsrc) {
  __builtin_amdgcn_global_load_lds(
      (__attribute__((address_space(1))) unsigned int*)(void*)(gsrc),
      (__attribute__((address_space(3))) unsigned int*)lds_uniform,
      16, 0, 0);
}

// ---------------- fp32 -> bf16 conversion ----------------
__global__ __launch_bounds__(256) void cvt_f32_bf16(const float4* __restrict__ src,
                                                    bf16x4* __restrict__ dst, int n4) {
  int i = blockIdx.x * 256 + threadIdx.x;
  if (i >= n4) return;
  float4 v = src[i];
  bf16x4 o;
  o[0] = (bf16)v.x; o[1] = (bf16)v.y; o[2] = (bf16)v.z; o[3] = (bf16)v.w;
  dst[i] = o;
}

// ---------------- GEMM core: C(128x128) = A[M,K] @ W[N,K]^T, K=1024, BK=32 ----------------
// 16 NAMED accumulators (no array -> nothing for RA/SROA to demote to scratch).
#define GEMM_ACC_DECL                              \
  floatx4 c00 = {}, c01 = {}, c02 = {}, c03 = {};  \
  floatx4 c10 = {}, c11 = {}, c12 = {}, c13 = {};  \
  floatx4 c20 = {}, c21 = {}, c22 = {}, c23 = {};  \
  floatx4 c30 = {}, c31 = {}, c32 = {}, c33 = {};

#define GEMM_MAINLOOP(Aptr, Bptr)                                              \
  for (int kt = 0; kt < 32; ++kt) {                                            \
    const int k0 = kt * 32;                                                    \
    __syncthreads();                                                           \
    _Pragma("unroll")                                                          \
    for (int j = 0; j < 2; ++j) {                                              \
      const int c = w * 64 + lane + 256 * j;                                   \
      const int row = c >> 2, seg = c & 3;                                     \
      gload_lds16((char*)As + (w * 64 + 256 * j) * 16,                         \
                  (Aptr) + (size_t)(bm + row) * D_MODEL + k0 + seg * 8);       \
      gload_lds16((char*)Bs + (w * 64 + 256 * j) * 16,                         \
                  (Bptr) + (size_t)(bn + row) * D_MODEL + k0 + seg * 8);       \
    }                                                                          \
    __syncthreads();                                                           \
    const bf16* Abase = &As[(wr * 64 + r) * 32 + g * 8];                       \
    const bf16* Bbase = &Bs[(wc * 64 + r) * 32 + g * 8];                       \
    bf16x8 a0 = *(const bf16x8*)(Abase + 0 * 512);                             \
    bf16x8 a1 = *(const bf16x8*)(Abase + 1 * 512);                             \
    bf16x8 a2 = *(const bf16x8*)(Abase + 2 * 512);                             \
    bf16x8 a3 = *(const bf16x8*)(Abase + 3 * 512);                             \
    bf16x8 b0 = *(const bf16x8*)(Bbase + 0 * 512);                             \
    bf16x8 b1 = *(const bf16x8*)(Bbase + 1 * 512);                             \
    bf16x8 b2 = *(const bf16x8*)(Bbase + 2 * 512);                             \
    bf16x8 b3 = *(const bf16x8*)(Bbase + 3 * 512);                             \
    c00 = mfma16(a0, b0, c00); c01 = mfma16(a0, b1, c01);                      \
    c02 = mfma16(a0, b2, c02); c03 = mfma16(a0, b3, c03);                      \
    c10 = mfma16(a1, b0, c10); c11 = mfma16(a1, b1, c11);                      \
    c12 = mfma16(a1, b2, c12); c13 = mfma16(a1, b3, c13);                      \
    c20 = mfma16(a2, b0, c20); c21 = mfma16(a2, b1, c21);                      \
    c22 = mfma16(a2, b2, c22); c23 = mfma16(a2, b3, c23);                      \
    c30 = mfma16(a3, b0, c30); c31 = mfma16(a3, b1, c31);                      \
    c32 = mfma16(a3, b2, c32); c33 = mfma16(a3, b3, c33);                      \
  }

// ---------------- QKV projection, RoPE fused, layout transform ----------------
#define QKV_EPI(mm, nn, CV)                                                    \
  _Pragma("unroll")                                                            \
  for (int reg = 0; reg < 4; ++reg) {                                          \
    const int grow = bm + wr * 64 + mm * 16 + g * 4 + reg;                     \
    const int gcol = bn + wc * 64 + nn * 16 + r;                               \
    const int b_ = grow >> 11, s_ = grow & (SEQ - 1);                          \
    const int h_ = gcol >> 6, d_ = gcol & 63;                                  \
    float v = CV[reg];                                                         \
    if (z < 2) {                                                               \
      float p = __shfl_xor(v, 1);                                              \
      float ang = (float)tokpos[s_] * exp2f(-(float)(d_ >> 1) * ROPE_L2);      \
      float sn, cs;                                                            \
      sincosf(ang, &sn, &cs);                                                  \
      float res = ((d_ & 1) == 0) ? (cs * v - sn * p) : (sn * p + cs * v);     \
      bf16* dst = (z == 0) ? Qd : Kd;                                          \
      dst[(((size_t)(b_ * NH + h_)) * SEQ + s_) * DKH + d_] = (bf16)res;       \
    } else {                                                                   \
      Vd[(((size_t)(b_ * NH + h_)) * DKH + d_) * SEQ + s_] = (bf16)v;          \
    }                                                                          \
  }

// z=0: Q -> Qd [B,H,S,dk] (RoPE). z=1: K -> Kd (RoPE). z=2: V -> Vd [B,H,dk,S] (transposed).
__global__ __launch_bounds__(256, 2) void gemm_qkv(
    const bf16* __restrict__ A,
    const bf16* __restrict__ W0, const bf16* __restrict__ W1, const bf16* __restrict__ W2,
    bf16* __restrict__ Qd, bf16* __restrict__ Kd, bf16* __restrict__ Vd,
    const int* __restrict__ tokpos) {
  __shared__ bf16 As[128 * 32];
  __shared__ bf16 Bs[128 * 32];
  const int z = blockIdx.z;
  const bf16* Bw = (z == 0) ? W0 : (z == 1) ? W1 : W2;
  const int tid = threadIdx.x, lane = tid & 63, w = tid >> 6;
  const int wr = w >> 1, wc = w & 1;
  const int bm = blockIdx.y * 128, bn = blockIdx.x * 128;
  const int r = lane & 15, g = lane >> 4;
  GEMM_ACC_DECL
  GEMM_MAINLOOP(A, Bw)

  QKV_EPI(0, 0, c00) QKV_EPI(0, 1, c01) QKV_EPI(0, 2, c02) QKV_EPI(0, 3, c03)
  QKV_EPI(1, 0, c10) QKV_EPI(1, 1, c11) QKV_EPI(1, 2, c12) QKV_EPI(1, 3, c13)
  QKV_EPI(2, 0, c20) QKV_EPI(2, 1, c21) QKV_EPI(2, 2, c22) QKV_EPI(2, 3, c23)
  QKV_EPI(3, 0, c30) QKV_EPI(3, 1, c31) QKV_EPI(3, 2, c32) QKV_EPI(3, 3, c33)
}

// ---------------- output projection: d_out = AO @ Wo^T (fp32 row-major) ----------------
#define OUT_EPI(mm, nn, CV)                                                    \
  _Pragma("unroll")                                                            \
  for (int reg = 0; reg < 4; ++reg) {                                          \
    const int grow = bm + wr * 64 + mm * 16 + g * 4 + reg;                     \
    const int gcol = bn + wc * 64 + nn * 16 + r;                               \
    C[(size_t)grow * D_MODEL + gcol] = CV[reg];                                \
  }

__global__ __launch_bounds__(256, 2) void gemm_out(const bf16* __restrict__ A,
                                                   const bf16* __restrict__ Bw,
                                                   float* __restrict__ C) {
  __shared__ bf16 As[128 * 32];
  __shared__ bf16 Bs[128 * 32];
  const int tid = threadIdx.x, lane = tid & 63, w = tid >> 6;
  const int wr = w >> 1, wc = w & 1;
  const int bm = blockIdx.y * 128, bn = blockIdx.x * 128;
  const int r = lane & 15, g = lane >> 4;
  GEMM_ACC_DECL
  GEMM_MAINLOOP(A, Bw)
  OUT_EPI(0, 0, c00) OUT_EPI(0, 1, c01) OUT_EPI(0, 2, c02) OUT_EPI(0, 3, c03)
  OUT_EPI(1, 0, c10) OUT_EPI(1, 1, c11) OUT_EPI(1, 2, c12) OUT_EPI(1, 3, c13)
  OUT_EPI(2, 0, c20) OUT_EPI(2, 1, c21) OUT_EPI(2, 2, c22) OUT_EPI(2, 3, c23)
  OUT_EPI(3, 0, c30) OUT_EPI(3, 1, c31) OUT_EPI(3, 2, c32) OUT_EPI(3, 3, c33)
}

// ---------------- causal flash attention ----------------
// grid (32, 64): x = q-tile of 64 rows, y = b*16+h. 4 waves x 16 q-rows.
// Q [B,H,S,64] bf16; K [B,H,S,64] bf16; Vt [B,H,64,S] bf16. AO [B,S,1024] bf16.
__global__ __launch_bounds__(256, 2) void attn64(const bf16* __restrict__ Q,
                                                 const bf16* __restrict__ Kk,
                                                 const bf16* __restrict__ Vt,
                                                 bf16* __restrict__ AO) {
  const int bh = blockIdx.y;
  const int b = bh >> 4, h = bh & 15;
  const int qt = blockIdx.x;
  const int tid = threadIdx.x, lane = tid & 63, w = tid >> 6;
  const int r = lane & 15, g = lane >> 4;
  const int q0 = qt * 64 + w * 16;

  const bf16* Qb = Q + ((size_t)bh * SEQ) * DKH;
  const bf16* Kb = Kk + ((size_t)bh * SEQ) * DKH;
  const bf16* Vb = Vt + ((size_t)bh * DKH) * SEQ;

  __shared__ bf16 Ks[64 * 64];     // [token][d], XOR-swizzled
  __shared__ bf16 Vs[64 * 64];     // [d][token], XOR-swizzled
  __shared__ bf16 Ps[4][16 * 64];  // per-wave P, XOR-swizzled

  bf16x8 qf[2];
#pragma unroll
  for (int ks = 0; ks < 2; ++ks)
    qf[ks] = *(const bf16x8*)(Qb + (size_t)(q0 + r) * DKH + ks * 32 + g * 8);

  floatx4 o[4] = {};
  float m_[4], l_[4];
#pragma unroll
  for (int i = 0; i < 4; ++i) { m_[i] = -1e30f; l_[i] = 0.f; }

  const int nt = qt + 1;
  for (int t = 0; t < nt; ++t) {
    const int t0 = t * 64;
    __syncthreads();
    // stage K (8KB contiguous) and V^T (64 rows x 128B, row stride 4KB), source pre-swizzled
#pragma unroll
    for (int j = 0; j < 2; ++j) {
      const int L = (w * 64 + lane + 256 * j) * 16;
      const int S = L ^ (((L >> 7) & 7) << 4);
      gload_lds16((char*)Ks + (w * 64 + 256 * j) * 16,
                  (const char*)(Kb + (size_t)t0 * DKH) + S);
      const int row = S >> 7, seg = S & 127;
      gload_lds16((char*)Vs + (w * 64 + 256 * j) * 16,
                  (const char*)Vb + (size_t)row * (SEQ * 2) + t0 * 2 + seg);
    }
    __syncthreads();

    // scores = Q @ K^T  (16 q-rows x 64 tokens)
    floatx4 sc[4];
#pragma unroll
    for (int nf = 0; nf < 4; ++nf) {
      sc[nf] = floatx4{0.f, 0.f, 0.f, 0.f};
#pragma unroll
      for (int ks = 0; ks < 2; ++ks) {
        const int row = nf * 16 + r;
        int byteoff = row * 128 + ks * 64 + g * 16;
        byteoff ^= ((row & 7) << 4);
        bf16x8 kf = *(const bf16x8*)((const char*)Ks + byteoff);
        sc[nf] = mfma16(qf[ks], kf, sc[nf]);
      }
    }

    const bool edge = (t0 + 63 > q0);
#pragma unroll
    for (int reg = 0; reg < 4; ++reg) {
      const int qrow = q0 + g * 4 + reg;
      float mx = -1e30f;
#pragma unroll
      for (int nf = 0; nf < 4; ++nf) {
        float s = sc[nf][reg] * 0.125f;  // 1/sqrt(64)
        if (edge && (t0 + nf * 16 + r > qrow)) s = -1e30f;
        sc[nf][reg] = s;
        mx = fmaxf(mx, s);
      }
#pragma unroll
      for (int off = 1; off < 16; off <<= 1) mx = fmaxf(mx, __shfl_xor(mx, off));
      const float mnew = fmaxf(m_[reg], mx);
      const float corr = __expf(m_[reg] - mnew);
      float rs = 0.f;
      const int prow = g * 4 + reg;
#pragma unroll
      for (int nf = 0; nf < 4; ++nf) {
        float p = __expf(sc[nf][reg] - mnew);
        rs += p;
        int pb = prow * 128 + (nf * 16 + r) * 2;
        pb ^= ((prow & 7) << 4);
        *(bf16*)((char*)Ps[w] + pb) = (bf16)p;
      }
#pragma unroll
      for (int off = 1; off < 16; off <<= 1) rs += __shfl_xor(rs, off);
      l_[reg] = l_[reg] * corr + rs;
      m_[reg] = mnew;
#pragma unroll
      for (int nf = 0; nf < 4; ++nf) o[nf][reg] *= corr;
    }
    // make P writes visible across lanes of this wave before ds_read
    asm volatile("s_waitcnt lgkmcnt(0)" ::: "memory");

    // O += P @ V
#pragma unroll
    for (int nf = 0; nf < 4; ++nf) {
#pragma unroll
      for (int ks = 0; ks < 2; ++ks) {
        int ab = r * 128 + ks * 64 + g * 16;
        ab ^= ((r & 7) << 4);
        bf16x8 pf = *(const bf16x8*)((const char*)Ps[w] + ab);
        const int vrow = nf * 16 + r;
        int vb = vrow * 128 + ks * 64 + g * 16;
        vb ^= ((vrow & 7) << 4);
        bf16x8 vf = *(const bf16x8*)((const char*)Vs + vb);
        o[nf] = mfma16(pf, vf, o[nf]);
      }
    }
  }

  // finalize and write AO[b, s, h*64+d]
#pragma unroll
  for (int nf = 0; nf < 4; ++nf)
#pragma unroll
    for (int reg = 0; reg < 4; ++reg) {
      const int s = q0 + g * 4 + reg;
      const int d = nf * 16 + r;
      const float val = o[nf][reg] / l_[reg];
      AO[((size_t)(b * SEQ + s)) * D_MODEL + h * DKH + d] = (bf16)val;
    }
}

// ---------------- launcher ----------------
extern "C" void kernel_launch(void* const* d_in, const int* in_sizes, int n_in,
                              void* d_out, int out_size, void* d_ws, size_t ws_size,
                              hipStream_t stream) {
  const float* x = (const float*)d_in[0];
  const int* tokpos = (const int*)d_in[1];
  const float* Wq = (const float*)d_in[2];
  const float* Wk = (const float*)d_in[3];
  const float* Wv = (const float*)d_in[4];
  const float* Wo = (const float*)d_in[5];
  float* out = (float*)d_out;

  char* ws = (char*)d_ws;
  if (ws_size < (72ull << 20)) return;  // need 72 MiB scratch

  bf16* xb  = (bf16*)(ws);                     // 16 MiB [8192,1024]
  bf16* wb0 = (bf16*)(ws + (16ull << 20));     // 2 MiB each
  bf16* wb1 = (bf16*)(ws + (18ull << 20));
  bf16* wb2 = (bf16*)(ws + (20ull << 20));
  bf16* wb3 = (bf16*)(ws + (22ull << 20));
  bf16* Qb  = (bf16*)(ws + (24ull << 20));     // 16 MiB [B,H,S,64]
  bf16* Kb  = (bf16*)(ws + (40ull << 20));     // 16 MiB
  bf16* Vt  = (bf16*)(ws + (56ull << 20));     // 16 MiB [B,H,64,S]
  bf16* AO  = (bf16*)(ws);                     // reuse xb region (dead after QKV)

  cvt_f32_bf16<<<8192, 256, 0, stream>>>((const float4*)x, (bf16x4*)xb, 2097152);
  cvt_f32_bf16<<<1024, 256, 0, stream>>>((const float4*)Wq, (bf16x4*)wb0, 262144);
  cvt_f32_bf16<<<1024, 256, 0, stream>>>((const float4*)Wk, (bf16x4*)wb1, 262144);
  cvt_f32_bf16<<<1024, 256, 0, stream>>>((const float4*)Wv, (bf16x4*)wb2, 262144);
  cvt_f32_bf16<<<1024, 256, 0, stream>>>((const float4*)Wo, (bf16x4*)wb3, 262144);

  gemm_qkv<<<dim3(8, 64, 3), 256, 0, stream>>>(xb, wb0, wb1, wb2, Qb, Kb, Vt, tokpos);
  attn64<<<dim3(32, 64), 256, 0, stream>>>(Qb, Kb, Vt, AO);
  gemm_out<<<dim3(8, 64), 256, 0, stream>>>(AO, wb3, out);
}